// Round 1
// baseline (566.307 us; speedup 1.0000x reference)
//
#include <hip/hip_runtime.h>
#include <hip/hip_bf16.h>

#define B_SZ   16
#define L_SZ   8192
#define DM     64
#define DI     128
#define DSTATE 16
#define NCH    128      // scan chunks
#define CLEN   64       // L_SZ / NCH
#define CHUNK  48       // frontend tokens per block
#define CT     51       // CHUNK + 3 (conv halo)
#define NBLK_L 171      // ceil(8192/48)
#define LN_EPS 1e-3f

__device__ __forceinline__ float sigmoidf_(float v) { return 1.f / (1.f + __expf(-v)); }

// ---------------- Frontend: xin, xz, conv, u, dbc, dt, B, C, silu(z) ----------------
__global__ __launch_bounds__(256) void k_frontend(
    const float* __restrict__ x, const float* __restrict__ W_in, const float* __restrict__ b_in,
    const float* __restrict__ in_proj, const float* __restrict__ conv_w, const float* __restrict__ conv_b,
    const float* __restrict__ x_proj, const float* __restrict__ dt_w, const float* __restrict__ dt_b,
    float* __restrict__ xin_g, __hip_bfloat16* __restrict__ u_g, float* __restrict__ dt_g,
    float* __restrict__ B_g, float* __restrict__ C_g, __hip_bfloat16* __restrict__ sz_g)
{
    __shared__ float sm[6528 + 6528 + 192];   // 53 KB
    float* xs   = sm;          // [51][64]   (later reused as us[48][128])
    float* xins = sm + 3264;   // [51][64]
    float* xcs  = sm + 6528;   // [51][128]
    float* us   = sm;          // [48][128]  overlaps xs+xins (after barrier)
    float* dtr  = sm + 13056;  // [48][4]

    const int tid = threadIdx.x;
    const int b   = blockIdx.y;
    const int c0  = blockIdx.x * CHUNK;
    const int nt  = min(CHUNK, L_SZ - c0);
    const long long tokbase = (long long)b * L_SZ + c0;

    // P0: stage x rows r=0..50 (l = c0-3+r), zero outside [0,L)
    for (int idx = tid; idx < CT * 64; idx += 256) {
        int r = idx >> 6, k = idx & 63;
        int l = c0 - 3 + r;
        float v = 0.f;
        if (l >= 0 && l < L_SZ) v = x[((long long)b * L_SZ + l) * 64 + k];
        xs[idx] = v;
    }
    __syncthreads();

    // P1: xin = x @ W_in + b_in   (K=64, N=64)
    {
        const int o = tid & 63, tg = tid >> 6;
        int rof[13];
#pragma unroll
        for (int j = 0; j < 13; j++) { int r = tg * 13 + j; rof[j] = ((r < CT) ? r : CT - 1) * 64; }
        float acc[13];
        const float bi = b_in[o];
#pragma unroll
        for (int j = 0; j < 13; j++) acc[j] = bi;
        for (int k = 0; k < 64; k++) {
            float w = W_in[k * 64 + o];
#pragma unroll
            for (int j = 0; j < 13; j++) acc[j] += xs[rof[j] + k] * w;
        }
#pragma unroll
        for (int j = 0; j < 13; j++) {
            int r = tg * 13 + j;
            if (r < CT) {
                xins[r * 64 + o] = acc[j];
                int l = c0 - 3 + r;
                if (r >= 3 && l < L_SZ) xin_g[((long long)b * L_SZ + l) * 64 + o] = acc[j];
            }
        }
    }
    __syncthreads();

    // P2: xz = xin @ in_proj  (K=64, N=256); cols 0..127 -> xc (LDS), 128..255 -> silu(z) (global)
    {
        const int o = tid;  // 0..255
        for (int p = 0; p < 4; p++) {
            int rbase = p * 13;
            int rof[13];
#pragma unroll
            for (int j = 0; j < 13; j++) { int r = rbase + j; rof[j] = ((r < CT) ? r : CT - 1) * 64; }
            float acc[13];
#pragma unroll
            for (int j = 0; j < 13; j++) acc[j] = 0.f;
            for (int k = 0; k < 64; k++) {
                float w = in_proj[k * 256 + o];
#pragma unroll
                for (int j = 0; j < 13; j++) acc[j] += xins[rof[j] + k] * w;
            }
#pragma unroll
            for (int j = 0; j < 13; j++) {
                int r = rbase + j;
                if (r < CT) {
                    int l = c0 - 3 + r;
                    if (o < DI) {
                        xcs[r * 128 + o] = (l >= 0 && l < L_SZ) ? acc[j] : 0.f;
                    } else if (r >= 3 && l < L_SZ) {
                        float v = acc[j];
                        sz_g[((long long)b * L_SZ + l) * 128 + (o - 128)] = __float2bfloat16(v * sigmoidf_(v));
                    }
                }
            }
        }
    }
    __syncthreads();

    // P3: depthwise causal conv(4) + silu -> u
    for (int idx = tid; idx < CHUNK * DI; idx += 256) {
        int ct = idx >> 7, d = idx & 127;
        float4 cw = ((const float4*)conv_w)[d];
        float v = conv_b[d];
        v += xcs[(ct + 0) * 128 + d] * cw.x;
        v += xcs[(ct + 1) * 128 + d] * cw.y;
        v += xcs[(ct + 2) * 128 + d] * cw.z;
        v += xcs[(ct + 3) * 128 + d] * cw.w;
        float u = v * sigmoidf_(v);
        us[idx] = u;
        if (ct < nt) u_g[(tokbase + ct) * 128 + d] = __float2bfloat16(u);
    }
    __syncthreads();

    // P4: dbc = u @ x_proj  (K=128, N=36): cols 0..3 -> dtr (LDS), 4..19 -> B, 20..35 -> C
    {
        const int o = tid & 63, tg = tid >> 6;
        if (o < 36) {
            float acc[12];
#pragma unroll
            for (int j = 0; j < 12; j++) acc[j] = 0.f;
            for (int k = 0; k < 128; k++) {
                float w = x_proj[k * 36 + o];
#pragma unroll
                for (int j = 0; j < 12; j++) acc[j] += us[(tg * 12 + j) * 128 + k] * w;
            }
#pragma unroll
            for (int j = 0; j < 12; j++) {
                int ct = tg * 12 + j;
                if (o < 4) {
                    dtr[ct * 4 + o] = acc[j];
                } else if (ct < nt) {
                    if (o < 20) B_g[(tokbase + ct) * 16 + (o - 4)]  = acc[j];
                    else        C_g[(tokbase + ct) * 16 + (o - 20)] = acc[j];
                }
            }
        }
    }
    __syncthreads();

    // P5: dt = softplus(dtr @ dt_proj_w + dt_proj_b)  (K=4, N=128)
    {
        const int o = tid & 127, tg = tid >> 7;
        const float bo = dt_b[o];
        float w0 = dt_w[0 * 128 + o], w1 = dt_w[1 * 128 + o], w2 = dt_w[2 * 128 + o], w3 = dt_w[3 * 128 + o];
#pragma unroll
        for (int j = 0; j < 24; j++) {
            int ct = tg * 24 + j;
            float v = bo + dtr[ct * 4 + 0] * w0 + dtr[ct * 4 + 1] * w1 + dtr[ct * 4 + 2] * w2 + dtr[ct * 4 + 3] * w3;
            float sp = (v > 20.f) ? v : log1pf(__expf(v));
            if (ct < nt) dt_g[(tokbase + ct) * 128 + o] = sp;
        }
    }
}

// ---------------- Chunked selective scan: phase 1 (local) and phase 3 (final + epilogue) ----------------
template <int PHASE>
__global__ __launch_bounds__(128) void k_scan(
    const float* dt_g,  // NOT restrict (phase3 is paired with y_g writes; keep ordering safe)
    const __hip_bfloat16* __restrict__ u_g,
    const float* __restrict__ B_g, const float* __restrict__ C_g,
    const __hip_bfloat16* __restrict__ sz_g, const float* __restrict__ A_log,
    const float* __restrict__ D_skip,
    float* __restrict__ hl_ws, float* __restrict__ sdt_ws,
    const float* __restrict__ hin_ws, __hip_bfloat16* __restrict__ y_g)
{
    const int d = threadIdx.x;          // 0..127
    const int c = blockIdx.x, b = blockIdx.y;

    float A[16];
    {
        const float4* ap = (const float4*)(A_log + d * 16);
        float4 a0 = ap[0], a1 = ap[1], a2 = ap[2], a3 = ap[3];
        A[0] = -expf(a0.x); A[1] = -expf(a0.y); A[2] = -expf(a0.z); A[3] = -expf(a0.w);
        A[4] = -expf(a1.x); A[5] = -expf(a1.y); A[6] = -expf(a1.z); A[7] = -expf(a1.w);
        A[8] = -expf(a2.x); A[9] = -expf(a2.y); A[10] = -expf(a2.z); A[11] = -expf(a2.w);
        A[12] = -expf(a3.x); A[13] = -expf(a3.y); A[14] = -expf(a3.z); A[15] = -expf(a3.w);
    }
    float h[16];
    if (PHASE == 1) {
#pragma unroll
        for (int s = 0; s < 16; s++) h[s] = 0.f;
    } else {
        const float4* hp = (const float4*)(hin_ws + (((long long)b * NCH + c) * 128 + d) * 16);
        float4 h0 = hp[0], h1 = hp[1], h2 = hp[2], h3 = hp[3];
        h[0] = h0.x; h[1] = h0.y; h[2] = h0.z; h[3] = h0.w;
        h[4] = h1.x; h[5] = h1.y; h[6] = h1.z; h[7] = h1.w;
        h[8] = h2.x; h[9] = h2.y; h[10] = h2.z; h[11] = h2.w;
        h[12] = h3.x; h[13] = h3.y; h[14] = h3.z; h[15] = h3.w;
    }
    const float Dv = D_skip[d];
    float sdt = 0.f;
    const long long tok0 = (long long)b * L_SZ + (long long)c * CLEN;

    for (int i = 0; i < CLEN; i++) {
        const long long t = tok0 + i;
        float dtv = dt_g[t * 128 + d];
        float uv  = __bfloat162float(u_g[t * 128 + d]);
        const float4* Bp = (const float4*)(B_g + t * 16);
        float4 B0 = Bp[0], B1 = Bp[1], B2 = Bp[2], B3 = Bp[3];
        float Bv[16] = { B0.x, B0.y, B0.z, B0.w, B1.x, B1.y, B1.z, B1.w,
                         B2.x, B2.y, B2.z, B2.w, B3.x, B3.y, B3.z, B3.w };
        float du = dtv * uv;
#pragma unroll
        for (int s = 0; s < 16; s++)
            h[s] = __expf(dtv * A[s]) * h[s] + du * Bv[s];

        if (PHASE == 1) {
            sdt += dtv;
        } else {
            const float4* Cp = (const float4*)(C_g + t * 16);
            float4 C0 = Cp[0], C1 = Cp[1], C2 = Cp[2], C3 = Cp[3];
            float Cv[16] = { C0.x, C0.y, C0.z, C0.w, C1.x, C1.y, C1.z, C1.w,
                             C2.x, C2.y, C2.z, C2.w, C3.x, C3.y, C3.z, C3.w };
            float ysum = 0.f;
#pragma unroll
            for (int s = 0; s < 16; s++) ysum += h[s] * Cv[s];
            float szv = __bfloat162float(sz_g[t * 128 + d]);
            y_g[t * 128 + d] = __float2bfloat16((ysum + uv * Dv) * szv);
        }
    }

    if (PHASE == 1) {
        float* hp = hl_ws + (((long long)b * NCH + c) * 128 + d) * 16;
        float4* hp4 = (float4*)hp;
        hp4[0] = make_float4(h[0], h[1], h[2], h[3]);
        hp4[1] = make_float4(h[4], h[5], h[6], h[7]);
        hp4[2] = make_float4(h[8], h[9], h[10], h[11]);
        hp4[3] = make_float4(h[12], h[13], h[14], h[15]);
        sdt_ws[((long long)b * NCH + c) * 128 + d] = sdt;
    }
}

// ---------------- Chunk-boundary combine (sequential over 128 chunks, 32768 threads) ----------------
__global__ __launch_bounds__(256) void k_combine(
    const float* __restrict__ A_log, const float* __restrict__ hl_ws,
    const float* __restrict__ sdt_ws, float* __restrict__ hin_ws)
{
    int gid = blockIdx.x * 256 + threadIdx.x;   // 0..32767
    int b = gid >> 11;
    int rem = gid & 2047;     // d*16+s
    int d = rem >> 4, s = rem & 15;
    float A = -expf(A_log[d * 16 + s]);
    float h = 0.f;
    for (int c = 0; c < NCH; c++) {
        long long o = ((long long)b * NCH + c) * 2048 + rem;
        hin_ws[o] = h;
        float sdt = sdt_ws[((long long)b * NCH + c) * 128 + d];
        h = __expf(A * sdt) * h + hl_ws[o];
    }
}

// ---------------- Epilogue: out = LN(y @ out_proj + xin) ----------------
__global__ __launch_bounds__(256) void k_epilogue(
    const __hip_bfloat16* __restrict__ y_g, const float* __restrict__ xin_g,
    const float* __restrict__ Wout, const float* __restrict__ gamma, const float* __restrict__ beta,
    float* __restrict__ out)
{
    __shared__ float ys[32 * 128];   // 16 KB
    const long long t0 = (long long)blockIdx.x * 32;
    for (int idx = threadIdx.x; idx < 32 * 128; idx += 256)
        ys[idx] = __bfloat162float(y_g[t0 * 128 + idx]);
    __syncthreads();

    const int o = threadIdx.x & 63, tg = threadIdx.x >> 6;
    float acc[8];
#pragma unroll
    for (int j = 0; j < 8; j++) acc[j] = 0.f;
    for (int k = 0; k < 128; k++) {
        float w = Wout[k * 64 + o];
#pragma unroll
        for (int j = 0; j < 8; j++) acc[j] += ys[(tg * 8 + j) * 128 + k] * w;
    }
    const float g = gamma[o], bb = beta[o];
#pragma unroll
    for (int j = 0; j < 8; j++) {
        long long t = t0 + tg * 8 + j;
        float r = acc[j] + xin_g[t * 64 + o];
        float ssum = r;
#pragma unroll
        for (int m = 0; m < 6; m++) ssum += __shfl_xor(ssum, 1 << m, 64);
        float mu = ssum * (1.f / 64.f);
        float dv = r - mu;
        float vs = dv * dv;
#pragma unroll
        for (int m = 0; m < 6; m++) vs += __shfl_xor(vs, 1 << m, 64);
        float var = vs * (1.f / 64.f);
        out[t * 64 + o] = g * dv * rsqrtf(var + LN_EPS) + bb;
    }
}

extern "C" void kernel_launch(void* const* d_in, const int* in_sizes, int n_in,
                              void* d_out, int out_size, void* d_ws, size_t ws_size,
                              hipStream_t stream)
{
    const float* x       = (const float*)d_in[0];
    const float* W_in    = (const float*)d_in[1];
    const float* b_in    = (const float*)d_in[2];
    const float* in_proj = (const float*)d_in[3];
    const float* conv_w  = (const float*)d_in[4];
    const float* conv_b  = (const float*)d_in[5];
    const float* x_proj  = (const float*)d_in[6];
    const float* dt_w    = (const float*)d_in[7];
    const float* dt_b    = (const float*)d_in[8];
    const float* A_log   = (const float*)d_in[9];
    const float* D_skip  = (const float*)d_in[10];
    const float* Wout    = (const float*)d_in[11];
    const float* gamma   = (const float*)d_in[12];
    const float* beta    = (const float*)d_in[13];
    float* out = (float*)d_out;

    const long long NT = (long long)B_SZ * L_SZ;  // 131072 tokens
    char* ws = (char*)d_ws;
    float* xin_g = (float*)ws;            ws += NT * 64 * 4;    // 33.5 MB
    float* dt_g  = (float*)ws;            ws += NT * 128 * 4;   // 67 MB
    float* B_g   = (float*)ws;            ws += NT * 16 * 4;    // 8.4 MB
    float* C_g   = (float*)ws;            ws += NT * 16 * 4;    // 8.4 MB
    __hip_bfloat16* u_g  = (__hip_bfloat16*)ws; ws += NT * 128 * 2;  // 33.5 MB
    __hip_bfloat16* sz_g = (__hip_bfloat16*)ws; ws += NT * 128 * 2;  // 33.5 MB
    __hip_bfloat16* y_g  = (__hip_bfloat16*)ws; ws += NT * 128 * 2;  // 33.5 MB
    float* hl_ws  = (float*)ws;           ws += (long long)B_SZ * NCH * 2048 * 4;  // 16.8 MB
    float* sdt_ws = (float*)ws;           ws += (long long)B_SZ * NCH * 128 * 4;   // 1 MB
    float* hin_ws = (float*)ws;           ws += (long long)B_SZ * NCH * 2048 * 4;  // 16.8 MB
    // total ~241 MB

    k_frontend<<<dim3(NBLK_L, B_SZ), 256, 0, stream>>>(
        x, W_in, b_in, in_proj, conv_w, conv_b, x_proj, dt_w, dt_b,
        xin_g, u_g, dt_g, B_g, C_g, sz_g);

    k_scan<1><<<dim3(NCH, B_SZ), 128, 0, stream>>>(
        dt_g, u_g, B_g, C_g, sz_g, A_log, D_skip, hl_ws, sdt_ws, nullptr, nullptr);

    k_combine<<<128, 256, 0, stream>>>(A_log, hl_ws, sdt_ws, hin_ws);

    k_scan<3><<<dim3(NCH, B_SZ), 128, 0, stream>>>(
        dt_g, u_g, B_g, C_g, sz_g, A_log, D_skip, nullptr, nullptr, hin_ws, y_g);

    k_epilogue<<<4096, 256, 0, stream>>>(y_g, xin_g, Wout, gamma, beta, out);
}

// Round 2
// 406.168 us; speedup vs baseline: 1.3943x; 1.3943x over previous
//
#include <hip/hip_runtime.h>
#include <hip/hip_bf16.h>

#define B_SZ   16
#define L_SZ   8192
#define DM     64
#define DI     128
#define DSTATE 16
#define NCH    128      // scan chunks
#define CLEN   64       // L_SZ / NCH
#define CH     64       // frontend tokens per block
#define RT     80       // padded rows (5 mtiles of 16; 67 used)
#define PA     72       // LDS pitch (bf16) for 64-wide activations: 144B = 9*16B, 2-way banks
#define PU     136      // LDS pitch (bf16) for 128-wide activations: 272B = 17*16B, 2-way banks
#define PC     132      // LDS pitch (bf16) for conv input
#define LN_EPS 1e-3f

typedef float  f4 __attribute__((ext_vector_type(4)));
typedef short  s8 __attribute__((ext_vector_type(8)));
#define MFMA16 __builtin_amdgcn_mfma_f32_16x16x32_bf16

__device__ __forceinline__ float sigmoidf_(float v) { return 1.f / (1.f + __expf(-v)); }

// ---------------- Weight prep: fragment-linear bf16 granules ----------------
// Granule g holds 8 bf16 for lane=g&63 of one (ntile,kstep) B-fragment:
//   element j = B[kstep*32 + (lane>>4)*8 + j][ntile*16 + (lane&15)]
__global__ __launch_bounds__(256) void k_prep(
    const float* __restrict__ W_in, const float* __restrict__ in_proj,
    const float* __restrict__ x_proj, const float* __restrict__ Wout,
    __hip_bfloat16* __restrict__ Wf1, __hip_bfloat16* __restrict__ Wf2,
    __hip_bfloat16* __restrict__ Wf3, __hip_bfloat16* __restrict__ Wf4)
{
    const int tid = threadIdx.x;
    for (int g = tid; g < 512; g += 256) {          // W_in: 4 nt x 2 ks
        int lane = g & 63, ks = (g >> 6) & 1, nt = g >> 7;
        int n = nt * 16 + (lane & 15), kb = ks * 32 + (lane >> 4) * 8;
        for (int j = 0; j < 8; j++) Wf1[g * 8 + j] = __float2bfloat16(W_in[(kb + j) * 64 + n]);
    }
    for (int g = tid; g < 2048; g += 256) {         // in_proj: 16 nt x 2 ks
        int lane = g & 63, ks = (g >> 6) & 1, nt = g >> 7;
        int n = nt * 16 + (lane & 15), kb = ks * 32 + (lane >> 4) * 8;
        for (int j = 0; j < 8; j++) Wf2[g * 8 + j] = __float2bfloat16(in_proj[(kb + j) * 256 + n]);
    }
    for (int g = tid; g < 768; g += 256) {          // x_proj (pad N 36->48): 3 nt x 4 ks
        int lane = g & 63, ks = (g >> 6) & 3, nt = g >> 8;
        int n = nt * 16 + (lane & 15), kb = ks * 32 + (lane >> 4) * 8;
        for (int j = 0; j < 8; j++)
            Wf3[g * 8 + j] = __float2bfloat16(n < 36 ? x_proj[(kb + j) * 36 + n] : 0.f);
    }
    for (int g = tid; g < 1024; g += 256) {         // out_proj: 4 nt x 4 ks
        int lane = g & 63, ks = (g >> 6) & 3, nt = g >> 8;
        int n = nt * 16 + (lane & 15), kb = ks * 32 + (lane >> 4) * 8;
        for (int j = 0; j < 8; j++) Wf4[g * 8 + j] = __float2bfloat16(Wout[(kb + j) * 64 + n]);
    }
}

// ---------------- Frontend: xin, xz, conv, u, dbc, dt, B, C, silu(z) (MFMA) ----------------
__global__ __launch_bounds__(256) void k_frontend(
    const float* __restrict__ x, const float* __restrict__ b_in,
    const float* __restrict__ conv_w, const float* __restrict__ conv_b,
    const float* __restrict__ dt_w, const float* __restrict__ dt_b,
    const __hip_bfloat16* __restrict__ Wf1, const __hip_bfloat16* __restrict__ Wf2,
    const __hip_bfloat16* __restrict__ Wf3,
    float* __restrict__ xin_g, __hip_bfloat16* __restrict__ u_g, float* __restrict__ dt_g,
    float* __restrict__ B_g, float* __restrict__ C_g, __hip_bfloat16* __restrict__ sz_g)
{
    __shared__ __align__(16) char sm[41088];
    __hip_bfloat16* smA   = (__hip_bfloat16*)sm;             // [80][72] x (bf16)
    __hip_bfloat16* smB   = (__hip_bfloat16*)(sm + 11520);   // [80][72] xin (bf16)
    __hip_bfloat16* smU   = (__hip_bfloat16*)sm;             // [64][136] u (reuses smA/smB)
    float*          smDtr = (float*)(sm + 17408);            // [64][4]
    __hip_bfloat16* smC   = (__hip_bfloat16*)(sm + 23040);   // [67][132] xc

    const int tid = threadIdx.x;
    const int w = tid >> 6, lane = tid & 63;
    const int n16 = lane & 15, quad = lane >> 4;
    const int b = blockIdx.y, c0 = blockIdx.x * CH;
    const long long tokbase = (long long)b * L_SZ + c0;

    // stage x rows (r=0..66 real, 67..79 zero); row r <-> token l = c0-3+r
    for (int idx = tid; idx < RT * 64; idx += 256) {
        int r = idx >> 6, k = idx & 63;
        int l = c0 - 3 + r;
        float v = (r < 67 && l >= 0) ? x[((long long)b * L_SZ + l) * 64 + k] : 0.f;
        smA[r * PA + k] = __float2bfloat16(v);
    }
    __syncthreads();

    // GEMM1: xin = x @ W_in + b_in   (M=80, N=64, K=64); wave w -> ntile w
    {
        s8 b0 = *(const s8*)(Wf1 + ((w * 2 + 0) * 64 + lane) * 8);
        s8 b1 = *(const s8*)(Wf1 + ((w * 2 + 1) * 64 + lane) * 8);
        float bias = b_in[w * 16 + n16];
        for (int m = 0; m < 5; m++) {
            int ar = m * 16 + n16;
            s8 a0 = *(const s8*)(smA + ar * PA + quad * 8);
            s8 a1 = *(const s8*)(smA + ar * PA + 32 + quad * 8);
            f4 acc = {0.f, 0.f, 0.f, 0.f};
            acc = MFMA16(a0, b0, acc, 0, 0, 0);
            acc = MFMA16(a1, b1, acc, 0, 0, 0);
#pragma unroll
            for (int reg = 0; reg < 4; reg++) {
                int rr = m * 16 + quad * 4 + reg;
                float v = acc[reg] + bias;
                smB[rr * PA + w * 16 + n16] = __float2bfloat16(v);
                if (rr >= 3 && rr < 67)
                    xin_g[(tokbase + rr - 3) * 64 + w * 16 + n16] = v;
            }
        }
    }
    __syncthreads();

    // GEMM2: xz = xin @ in_proj  (N=256); wave w -> ntiles 4w..4w+3
    {
        s8 bf[4][2];
#pragma unroll
        for (int i = 0; i < 4; i++)
#pragma unroll
            for (int ks = 0; ks < 2; ks++)
                bf[i][ks] = *(const s8*)(Wf2 + (((w * 4 + i) * 2 + ks) * 64 + lane) * 8);
        for (int m = 0; m < 5; m++) {
            int ar = m * 16 + n16;
            s8 a0 = *(const s8*)(smB + ar * PA + quad * 8);
            s8 a1 = *(const s8*)(smB + ar * PA + 32 + quad * 8);
#pragma unroll
            for (int i = 0; i < 4; i++) {
                f4 acc = {0.f, 0.f, 0.f, 0.f};
                acc = MFMA16(a0, bf[i][0], acc, 0, 0, 0);
                acc = MFMA16(a1, bf[i][1], acc, 0, 0, 0);
                int cg = (w * 4 + i) * 16 + n16;
#pragma unroll
                for (int reg = 0; reg < 4; reg++) {
                    int rr = m * 16 + quad * 4 + reg;
                    float v = acc[reg];
                    if (cg < 128) {
                        if (rr < 67) {
                            int l = c0 - 3 + rr;
                            smC[rr * PC + cg] = __float2bfloat16(l >= 0 ? v : 0.f);
                        }
                    } else if (rr >= 3 && rr < 67) {
                        sz_g[(tokbase + rr - 3) * 128 + (cg - 128)] =
                            __float2bfloat16(v * sigmoidf_(v));
                    }
                }
            }
        }
    }
    __syncthreads();

    // conv(4) + silu -> u  (writes smU over dead smA/smB)
    for (int idx = tid; idx < CH * DI; idx += 256) {
        int ct = idx >> 7, d = idx & 127;
        float4 cw = ((const float4*)conv_w)[d];
        float v = conv_b[d];
        v += __bfloat162float(smC[(ct + 0) * PC + d]) * cw.x;
        v += __bfloat162float(smC[(ct + 1) * PC + d]) * cw.y;
        v += __bfloat162float(smC[(ct + 2) * PC + d]) * cw.z;
        v += __bfloat162float(smC[(ct + 3) * PC + d]) * cw.w;
        float u = v * sigmoidf_(v);
        u_g[(tokbase + ct) * 128 + d] = __float2bfloat16(u);
        smU[ct * PU + d] = __float2bfloat16(u);
    }
    __syncthreads();

    // GEMM3: dbc = u @ x_proj  (M=64, N=48(36), K=128); wave w -> mtile w
    {
        s8 bf3[3][4];
#pragma unroll
        for (int nt = 0; nt < 3; nt++)
#pragma unroll
            for (int ks = 0; ks < 4; ks++)
                bf3[nt][ks] = *(const s8*)(Wf3 + ((nt * 4 + ks) * 64 + lane) * 8);
        f4 acc[3] = {{0.f,0.f,0.f,0.f},{0.f,0.f,0.f,0.f},{0.f,0.f,0.f,0.f}};
        int ar = w * 16 + n16;
#pragma unroll
        for (int ks = 0; ks < 4; ks++) {
            s8 a = *(const s8*)(smU + ar * PU + ks * 32 + quad * 8);
#pragma unroll
            for (int nt = 0; nt < 3; nt++) acc[nt] = MFMA16(a, bf3[nt][ks], acc[nt], 0, 0, 0);
        }
#pragma unroll
        for (int nt = 0; nt < 3; nt++) {
            int c = nt * 16 + n16;
#pragma unroll
            for (int reg = 0; reg < 4; reg++) {
                int rr = w * 16 + quad * 4 + reg;
                float v = acc[nt][reg];
                long long t = tokbase + rr;
                if (c < 4)       smDtr[rr * 4 + c] = v;
                else if (c < 20) B_g[t * 16 + (c - 4)] = v;
                else if (c < 36) C_g[t * 16 + (c - 20)] = v;
            }
        }
    }
    __syncthreads();

    // dt = softplus(dtr @ dt_proj_w + dt_proj_b)
    {
        int o = tid & 127, half = tid >> 7;
        float w0 = dt_w[o], w1 = dt_w[128 + o], w2 = dt_w[256 + o], w3 = dt_w[384 + o];
        float bo = dt_b[o];
        for (int j = 0; j < 32; j++) {
            int ct = half * 32 + j;
            float v = bo + smDtr[ct * 4] * w0 + smDtr[ct * 4 + 1] * w1 +
                      smDtr[ct * 4 + 2] * w2 + smDtr[ct * 4 + 3] * w3;
            float sp = (v > 20.f) ? v : log1pf(__expf(v));
            dt_g[(tokbase + ct) * 128 + o] = sp;
        }
    }
}

// ---------------- Chunked selective scan: phase 1 (local) and phase 3 (final) ----------------
template <int PHASE>
__global__ __launch_bounds__(128) void k_scan(
    const float* dt_g,
    const __hip_bfloat16* __restrict__ u_g,
    const float* __restrict__ B_g, const float* __restrict__ C_g,
    const __hip_bfloat16* __restrict__ sz_g, const float* __restrict__ A_log,
    const float* __restrict__ D_skip,
    float* __restrict__ hl_ws, float* __restrict__ sdt_ws,
    const float* __restrict__ hin_ws, __hip_bfloat16* __restrict__ y_g)
{
    const int d = threadIdx.x;          // 0..127
    const int c = blockIdx.x, b = blockIdx.y;

    float A[16];
    {
        const float4* ap = (const float4*)(A_log + d * 16);
        float4 a0 = ap[0], a1 = ap[1], a2 = ap[2], a3 = ap[3];
        A[0] = -expf(a0.x); A[1] = -expf(a0.y); A[2] = -expf(a0.z); A[3] = -expf(a0.w);
        A[4] = -expf(a1.x); A[5] = -expf(a1.y); A[6] = -expf(a1.z); A[7] = -expf(a1.w);
        A[8] = -expf(a2.x); A[9] = -expf(a2.y); A[10] = -expf(a2.z); A[11] = -expf(a2.w);
        A[12] = -expf(a3.x); A[13] = -expf(a3.y); A[14] = -expf(a3.z); A[15] = -expf(a3.w);
    }
    float h[16];
    if (PHASE == 1) {
#pragma unroll
        for (int s = 0; s < 16; s++) h[s] = 0.f;
    } else {
        const float4* hp = (const float4*)(hin_ws + (((long long)b * NCH + c) * 128 + d) * 16);
        float4 h0 = hp[0], h1 = hp[1], h2 = hp[2], h3 = hp[3];
        h[0] = h0.x; h[1] = h0.y; h[2] = h0.z; h[3] = h0.w;
        h[4] = h1.x; h[5] = h1.y; h[6] = h1.z; h[7] = h1.w;
        h[8] = h2.x; h[9] = h2.y; h[10] = h2.z; h[11] = h2.w;
        h[12] = h3.x; h[13] = h3.y; h[14] = h3.z; h[15] = h3.w;
    }
    const float Dv = D_skip[d];
    float sdt = 0.f;
    const long long tok0 = (long long)b * L_SZ + (long long)c * CLEN;

    for (int i = 0; i < CLEN; i++) {
        const long long t = tok0 + i;
        float dtv = dt_g[t * 128 + d];
        float uv  = __bfloat162float(u_g[t * 128 + d]);
        const float4* Bp = (const float4*)(B_g + t * 16);
        float4 B0 = Bp[0], B1 = Bp[1], B2 = Bp[2], B3 = Bp[3];
        float Bv[16] = { B0.x, B0.y, B0.z, B0.w, B1.x, B1.y, B1.z, B1.w,
                         B2.x, B2.y, B2.z, B2.w, B3.x, B3.y, B3.z, B3.w };
        float du = dtv * uv;
#pragma unroll
        for (int s = 0; s < 16; s++)
            h[s] = __expf(dtv * A[s]) * h[s] + du * Bv[s];

        if (PHASE == 1) {
            sdt += dtv;
        } else {
            const float4* Cp = (const float4*)(C_g + t * 16);
            float4 C0 = Cp[0], C1 = Cp[1], C2 = Cp[2], C3 = Cp[3];
            float Cv[16] = { C0.x, C0.y, C0.z, C0.w, C1.x, C1.y, C1.z, C1.w,
                             C2.x, C2.y, C2.z, C2.w, C3.x, C3.y, C3.z, C3.w };
            float ysum = 0.f;
#pragma unroll
            for (int s = 0; s < 16; s++) ysum += h[s] * Cv[s];
            float szv = __bfloat162float(sz_g[t * 128 + d]);
            y_g[t * 128 + d] = __float2bfloat16((ysum + uv * Dv) * szv);
        }
    }

    if (PHASE == 1) {
        float4* hp4 = (float4*)(hl_ws + (((long long)b * NCH + c) * 128 + d) * 16);
        hp4[0] = make_float4(h[0], h[1], h[2], h[3]);
        hp4[1] = make_float4(h[4], h[5], h[6], h[7]);
        hp4[2] = make_float4(h[8], h[9], h[10], h[11]);
        hp4[3] = make_float4(h[12], h[13], h[14], h[15]);
        sdt_ws[((long long)b * NCH + c) * 128 + d] = sdt;
    }
}

// ---------------- Chunk-boundary combine ----------------
__global__ __launch_bounds__(256) void k_combine(
    const float* __restrict__ A_log, const float* __restrict__ hl_ws,
    const float* __restrict__ sdt_ws, float* __restrict__ hin_ws)
{
    int gid = blockIdx.x * 256 + threadIdx.x;   // 0..32767
    int b = gid >> 11;
    int rem = gid & 2047;     // d*16+s
    int d = rem >> 4;
    float A = -expf(A_log[rem]);
    float h = 0.f;
    for (int c = 0; c < NCH; c++) {
        long long o = ((long long)b * NCH + c) * 2048 + rem;
        hin_ws[o] = h;
        float sdt = sdt_ws[((long long)b * NCH + c) * 128 + d];
        h = __expf(A * sdt) * h + hl_ws[o];
    }
}

// ---------------- Epilogue: out = LN(y @ out_proj + xin)  (MFMA) ----------------
__global__ __launch_bounds__(256) void k_epilogue(
    const __hip_bfloat16* __restrict__ y_g, const float* __restrict__ xin_g,
    const __hip_bfloat16* __restrict__ Wf4, const float* __restrict__ gamma,
    const float* __restrict__ beta, float* __restrict__ out)
{
    __shared__ __align__(16) char sm[34048];
    __hip_bfloat16* yA  = (__hip_bfloat16*)sm;        // [64][136]
    float*          smR = (float*)(sm + 17408);       // [64][65]

    const int tid = threadIdx.x;
    const int w = tid >> 6, lane = tid & 63;
    const int n16 = lane & 15, quad = lane >> 4;
    const long long t0 = (long long)blockIdx.x * 64;

    for (int idx = tid; idx < 64 * 64; idx += 256) {
        int r = idx >> 6, cp = idx & 63;
        unsigned int v = ((const unsigned int*)y_g)[(t0 + r) * 64 + cp];
        *(unsigned int*)((char*)yA + r * 272 + cp * 4) = v;
    }
    __syncthreads();

    {
        s8 bf[4];
#pragma unroll
        for (int ks = 0; ks < 4; ks++)
            bf[ks] = *(const s8*)(Wf4 + ((w * 4 + ks) * 64 + lane) * 8);
#pragma unroll
        for (int m = 0; m < 4; m++) {
            int ar = m * 16 + n16;
            f4 acc = {0.f, 0.f, 0.f, 0.f};
#pragma unroll
            for (int ks = 0; ks < 4; ks++) {
                s8 a = *(const s8*)(yA + ar * PU + ks * 32 + quad * 8);
                acc = MFMA16(a, bf[ks], acc, 0, 0, 0);
            }
#pragma unroll
            for (int reg = 0; reg < 4; reg++) {
                int rr = m * 16 + quad * 4 + reg;
                smR[rr * 65 + w * 16 + n16] = acc[reg];
            }
        }
    }
    __syncthreads();

    {
        int o = tid & 63, wv = tid >> 6;
        float g = gamma[o], bb = beta[o];
        for (int j = 0; j < 16; j++) {
            int rr = wv * 16 + j;
            float r = smR[rr * 65 + o] + xin_g[(t0 + rr) * 64 + o];
            float s = r;
#pragma unroll
            for (int mS = 0; mS < 6; mS++) s += __shfl_xor(s, 1 << mS, 64);
            float mu = s * (1.f / 64.f);
            float dv = r - mu;
            float vs = dv * dv;
#pragma unroll
            for (int mS = 0; mS < 6; mS++) vs += __shfl_xor(vs, 1 << mS, 64);
            out[(t0 + rr) * 64 + o] = g * dv * rsqrtf(vs * (1.f / 64.f) + LN_EPS) + bb;
        }
    }
}

extern "C" void kernel_launch(void* const* d_in, const int* in_sizes, int n_in,
                              void* d_out, int out_size, void* d_ws, size_t ws_size,
                              hipStream_t stream)
{
    const float* x       = (const float*)d_in[0];
    const float* W_in    = (const float*)d_in[1];
    const float* b_in    = (const float*)d_in[2];
    const float* in_proj = (const float*)d_in[3];
    const float* conv_w  = (const float*)d_in[4];
    const float* conv_b  = (const float*)d_in[5];
    const float* x_proj  = (const float*)d_in[6];
    const float* dt_w    = (const float*)d_in[7];
    const float* dt_b    = (const float*)d_in[8];
    const float* A_log   = (const float*)d_in[9];
    const float* D_skip  = (const float*)d_in[10];
    const float* Wout    = (const float*)d_in[11];
    const float* gamma   = (const float*)d_in[12];
    const float* beta    = (const float*)d_in[13];
    float* out = (float*)d_out;

    const long long NT = (long long)B_SZ * L_SZ;  // 131072 tokens
    char* ws = (char*)d_ws;
    float* xin_g = (float*)ws;            ws += NT * 64 * 4;
    float* dt_g  = (float*)ws;            ws += NT * 128 * 4;
    float* B_g   = (float*)ws;            ws += NT * 16 * 4;
    float* C_g   = (float*)ws;            ws += NT * 16 * 4;
    __hip_bfloat16* u_g  = (__hip_bfloat16*)ws; ws += NT * 128 * 2;
    __hip_bfloat16* sz_g = (__hip_bfloat16*)ws; ws += NT * 128 * 2;
    __hip_bfloat16* y_g  = (__hip_bfloat16*)ws; ws += NT * 128 * 2;
    float* hl_ws  = (float*)ws;           ws += (long long)B_SZ * NCH * 2048 * 4;
    float* sdt_ws = (float*)ws;           ws += (long long)B_SZ * NCH * 128 * 4;
    float* hin_ws = (float*)ws;           ws += (long long)B_SZ * NCH * 2048 * 4;
    __hip_bfloat16* Wf1 = (__hip_bfloat16*)ws; ws += 4096 * 2;
    __hip_bfloat16* Wf2 = (__hip_bfloat16*)ws; ws += 16384 * 2;
    __hip_bfloat16* Wf3 = (__hip_bfloat16*)ws; ws += 6144 * 2;
    __hip_bfloat16* Wf4 = (__hip_bfloat16*)ws; ws += 8192 * 2;

    k_prep<<<1, 256, 0, stream>>>(W_in, in_proj, x_proj, Wout, Wf1, Wf2, Wf3, Wf4);

    k_frontend<<<dim3(L_SZ / CH, B_SZ), 256, 0, stream>>>(
        x, b_in, conv_w, conv_b, dt_w, dt_b, Wf1, Wf2, Wf3,
        xin_g, u_g, dt_g, B_g, C_g, sz_g);

    k_scan<1><<<dim3(NCH, B_SZ), 128, 0, stream>>>(
        dt_g, u_g, B_g, C_g, sz_g, A_log, D_skip, hl_ws, sdt_ws, nullptr, nullptr);

    k_combine<<<128, 256, 0, stream>>>(A_log, hl_ws, sdt_ws, hin_ws);

    k_scan<3><<<dim3(NCH, B_SZ), 128, 0, stream>>>(
        dt_g, u_g, B_g, C_g, sz_g, A_log, D_skip, nullptr, nullptr, hin_ws, y_g);

    k_epilogue<<<2048, 256, 0, stream>>>(y_g, xin_g, Wf4, gamma, beta, out);
}

// Round 5
// 310.356 us; speedup vs baseline: 1.8247x; 1.3087x over previous
//
#include <hip/hip_runtime.h>
#include <hip/hip_bf16.h>

#define B_SZ   16
#define L_SZ   8192
#define DM     64
#define DI     128
#define NCH    128      // scan chunks
#define CLEN   64       // L_SZ / NCH
#define CH     64       // frontend tokens per block
#define RT     80       // padded rows (5 mtiles of 16; 67 used)
#define PA     72       // LDS pitch (u16) for 64-wide acts: 144B
#define PU     136      // LDS pitch (u16) for 128-wide acts: 272B
#define PC     132      // LDS pitch (u16) for conv input: 264B
#define LN_EPS 1e-3f

typedef float  f4 __attribute__((ext_vector_type(4)));
typedef short  s8 __attribute__((ext_vector_type(8)));
typedef unsigned short u16;
typedef unsigned int   u32;
#define MFMA16 __builtin_amdgcn_mfma_f32_16x16x32_bf16

__device__ __forceinline__ u16 f2bfu(float f) {
    u32 u = __float_as_uint(f);
    return (u16)((u + 0x7FFFu + ((u >> 16) & 1u)) >> 16);
}
__device__ __forceinline__ u32 pk2bf(float a, float b) {
    return (u32)f2bfu(a) | ((u32)f2bfu(b) << 16);
}
__device__ __forceinline__ float bflo(u32 u) { return __uint_as_float(u << 16); }
__device__ __forceinline__ float bfhi(u32 u) { return __uint_as_float(u & 0xFFFF0000u); }
__device__ __forceinline__ float bfu2f(u16 h) { return __uint_as_float((u32)h << 16); }
__device__ __forceinline__ float fsig(float v) {
    return __builtin_amdgcn_rcpf(1.f + __expf(-v));
}
__device__ __forceinline__ float fsp(float v) {   // softplus
    return fmaxf(v, 0.f) + __logf(1.f + __expf(-fabsf(v)));
}

// ---------------- Weight prep: fragment-linear bf16 granules ----------------
__global__ __launch_bounds__(256) void k_prep(
    const float* __restrict__ W_in, const float* __restrict__ in_proj,
    const float* __restrict__ x_proj, const float* __restrict__ Wout,
    u16* __restrict__ Wf1, u16* __restrict__ Wf2,
    u16* __restrict__ Wf3, u16* __restrict__ Wf4)
{
    const int tid = threadIdx.x;
    for (int g = tid; g < 512; g += 256) {          // W_in: 4 nt x 2 ks
        int lane = g & 63, ks = (g >> 6) & 1, nt = g >> 7;
        int n = nt * 16 + (lane & 15), kb = ks * 32 + (lane >> 4) * 8;
        for (int j = 0; j < 8; j++) Wf1[g * 8 + j] = f2bfu(W_in[(kb + j) * 64 + n]);
    }
    for (int g = tid; g < 2048; g += 256) {         // in_proj: 16 nt x 2 ks
        int lane = g & 63, ks = (g >> 6) & 1, nt = g >> 7;
        int n = nt * 16 + (lane & 15), kb = ks * 32 + (lane >> 4) * 8;
        for (int j = 0; j < 8; j++) Wf2[g * 8 + j] = f2bfu(in_proj[(kb + j) * 256 + n]);
    }
    for (int g = tid; g < 768; g += 256) {          // x_proj (pad N 36->48): 3 nt x 4 ks
        int lane = g & 63, ks = (g >> 6) & 3, nt = g >> 8;
        int n = nt * 16 + (lane & 15), kb = ks * 32 + (lane >> 4) * 8;
        for (int j = 0; j < 8; j++)
            Wf3[g * 8 + j] = f2bfu(n < 36 ? x_proj[(kb + j) * 36 + n] : 0.f);
    }
    for (int g = tid; g < 1024; g += 256) {         // out_proj: 4 nt x 4 ks
        int lane = g & 63, ks = (g >> 6) & 3, nt = g >> 8;
        int n = nt * 16 + (lane & 15), kb = ks * 32 + (lane >> 4) * 8;
        for (int j = 0; j < 8; j++) Wf4[g * 8 + j] = f2bfu(Wout[(kb + j) * 64 + n]);
    }
}

// ---------------- Frontend ----------------
__global__ __launch_bounds__(256) void k_frontend(
    const float* __restrict__ x, const float* __restrict__ b_in,
    const float* __restrict__ conv_w, const float* __restrict__ conv_b,
    const float* __restrict__ dt_w, const float* __restrict__ dt_b,
    const u16* __restrict__ Wf1, const u16* __restrict__ Wf2, const u16* __restrict__ Wf3,
    float* __restrict__ xin_g, u16* __restrict__ u_g, float* __restrict__ dt_g,
    float* __restrict__ B_g, float* __restrict__ C_g, u16* __restrict__ sz_g)
{
    __shared__ __align__(16) char sm[41088];
    u16*   smA   = (u16*)sm;              // [80][72] x (bf16)
    u16*   smB   = (u16*)(sm + 11520);    // [80][72] xin
    u16*   smU   = (u16*)sm;              // [64][136] u (reuses smA/smB)
    float* smDtr = (float*)(sm + 17408);  // [64][4]
    u16*   smC   = (u16*)(sm + 23040);    // [67][132] xc

    const int tid = threadIdx.x;
    const int w = tid >> 6, lane = tid & 63;
    const int n16 = lane & 15, quad = lane >> 4;
    const int b = blockIdx.y, c0 = blockIdx.x * CH;
    const long long tokbase = (long long)b * L_SZ + c0;

    // P0: stage x rows (bf16), float4-vectorized
    for (int idx = tid; idx < RT * 16; idx += 256) {
        int r = idx >> 4, c4 = idx & 15;
        int l = c0 - 3 + r;
        float4 v = make_float4(0.f, 0.f, 0.f, 0.f);
        if (r < 67 && l >= 0)
            v = *(const float4*)(x + ((long long)b * L_SZ + l) * 64 + c4 * 4);
        *(uint2*)((char*)smA + r * 144 + c4 * 8) = make_uint2(pk2bf(v.x, v.y), pk2bf(v.z, v.w));
    }
    __syncthreads();

    // GEMM1: xin = x @ W_in + b_in
    {
        s8 b0 = *(const s8*)(Wf1 + ((w * 2 + 0) * 64 + lane) * 8);
        s8 b1 = *(const s8*)(Wf1 + ((w * 2 + 1) * 64 + lane) * 8);
        float bias = b_in[w * 16 + n16];
        for (int m = 0; m < 5; m++) {
            int ar = m * 16 + n16;
            s8 a0 = *(const s8*)(smA + ar * PA + quad * 8);
            s8 a1 = *(const s8*)(smA + ar * PA + 32 + quad * 8);
            f4 acc = {0.f, 0.f, 0.f, 0.f};
            acc = MFMA16(a0, b0, acc, 0, 0, 0);
            acc = MFMA16(a1, b1, acc, 0, 0, 0);
#pragma unroll
            for (int reg = 0; reg < 4; reg++) {
                int rr = m * 16 + quad * 4 + reg;
                float v = acc[reg] + bias;
                smB[rr * PA + w * 16 + n16] = f2bfu(v);
                if (rr >= 3 && rr < 67)
                    xin_g[(tokbase + rr - 3) * 64 + w * 16 + n16] = v;
            }
        }
    }
    __syncthreads();

    // GEMM2: xz = xin @ in_proj (waves 0-1 -> xc, waves 2-3 -> silu(z))
    {
        s8 bf[4][2];
#pragma unroll
        for (int i = 0; i < 4; i++)
#pragma unroll
            for (int ks = 0; ks < 2; ks++)
                bf[i][ks] = *(const s8*)(Wf2 + (((w * 4 + i) * 2 + ks) * 64 + lane) * 8);
        for (int m = 0; m < 5; m++) {
            int ar = m * 16 + n16;
            s8 a0 = *(const s8*)(smB + ar * PA + quad * 8);
            s8 a1 = *(const s8*)(smB + ar * PA + 32 + quad * 8);
#pragma unroll
            for (int i = 0; i < 4; i++) {
                f4 acc = {0.f, 0.f, 0.f, 0.f};
                acc = MFMA16(a0, bf[i][0], acc, 0, 0, 0);
                acc = MFMA16(a1, bf[i][1], acc, 0, 0, 0);
                int cg = (w * 4 + i) * 16 + n16;
#pragma unroll
                for (int reg = 0; reg < 4; reg++) {
                    int rr = m * 16 + quad * 4 + reg;
                    float v = acc[reg];
                    if (cg < 128) {                     // wave-uniform branch
                        if (rr < 67) {
                            int l = c0 - 3 + rr;
                            smC[rr * PC + cg] = f2bfu(l >= 0 ? v : 0.f);
                        }
                    } else if (rr >= 3 && rr < 67) {
                        sz_g[(tokbase + rr - 3) * 128 + (cg - 128)] = f2bfu(v * fsig(v));
                    }
                }
            }
        }
    }
    __syncthreads();

    // conv(4) + silu -> u ; channel-pair per lane, sliding row window
    {
        const int d2 = lane * 2, ctb = w * 16;
        float4 cw0 = ((const float4*)conv_w)[d2];
        float4 cw1 = ((const float4*)conv_w)[d2 + 1];
        float cb0 = conv_b[d2], cb1 = conv_b[d2 + 1];
        u32 r0 = *(const u32*)((char*)smC + (ctb + 0) * 264 + lane * 4);
        u32 r1 = *(const u32*)((char*)smC + (ctb + 1) * 264 + lane * 4);
        u32 r2 = *(const u32*)((char*)smC + (ctb + 2) * 264 + lane * 4);
#pragma unroll 4
        for (int j = 0; j < 16; j++) {
            int ct = ctb + j;
            u32 r3 = *(const u32*)((char*)smC + (ct + 3) * 264 + lane * 4);
            float v0 = cb0 + bflo(r0) * cw0.x + bflo(r1) * cw0.y + bflo(r2) * cw0.z + bflo(r3) * cw0.w;
            float v1 = cb1 + bfhi(r0) * cw1.x + bfhi(r1) * cw1.y + bfhi(r2) * cw1.z + bfhi(r3) * cw1.w;
            u32 pk = pk2bf(v0 * fsig(v0), v1 * fsig(v1));
            *(u32*)(u_g + (tokbase + ct) * 128 + d2) = pk;
            *(u32*)(smU + ct * PU + d2) = pk;
            r0 = r1; r1 = r2; r2 = r3;
        }
    }
    __syncthreads();

    // GEMM3: dbc = u @ x_proj  (M=64, N=48(36), K=128); wave w -> mtile w
    {
        s8 bf3[3][4];
#pragma unroll
        for (int nt = 0; nt < 3; nt++)
#pragma unroll
            for (int ks = 0; ks < 4; ks++)
                bf3[nt][ks] = *(const s8*)(Wf3 + ((nt * 4 + ks) * 64 + lane) * 8);
        f4 acc[3] = {{0.f,0.f,0.f,0.f},{0.f,0.f,0.f,0.f},{0.f,0.f,0.f,0.f}};
        int ar = w * 16 + n16;
#pragma unroll
        for (int ks = 0; ks < 4; ks++) {
            s8 a = *(const s8*)(smU + ar * PU + ks * 32 + quad * 8);
#pragma unroll
            for (int nt = 0; nt < 3; nt++) acc[nt] = MFMA16(a, bf3[nt][ks], acc[nt], 0, 0, 0);
        }
#pragma unroll
        for (int nt = 0; nt < 3; nt++) {
            int c = nt * 16 + n16;
#pragma unroll
            for (int reg = 0; reg < 4; reg++) {
                int rr = w * 16 + quad * 4 + reg;
                float v = acc[nt][reg];
                long long t = tokbase + rr;
                if (c < 4)       smDtr[rr * 4 + c] = v;
                else if (c < 20) B_g[t * 16 + (c - 4)] = v;
                else if (c < 36) C_g[t * 16 + (c - 20)] = v;
            }
        }
    }
    __syncthreads();

    // dt = softplus(dtr @ dt_proj_w + dt_proj_b) -> fp32, float2 stores
    {
        const int o2 = lane * 2, grp = w;
        float w00 = dt_w[o2],       w01 = dt_w[o2 + 1];
        float w10 = dt_w[128 + o2], w11 = dt_w[128 + o2 + 1];
        float w20 = dt_w[256 + o2], w21 = dt_w[256 + o2 + 1];
        float w30 = dt_w[384 + o2], w31 = dt_w[384 + o2 + 1];
        float b0 = dt_b[o2], b1 = dt_b[o2 + 1];
#pragma unroll 4
        for (int j = 0; j < 16; j++) {
            int ct = grp * 16 + j;
            float4 q = *(const float4*)(smDtr + ct * 4);
            float v0 = b0 + q.x * w00 + q.y * w10 + q.z * w20 + q.w * w30;
            float v1 = b1 + q.x * w01 + q.y * w11 + q.z * w21 + q.w * w31;
            *(float2*)(dt_g + (tokbase + ct) * 128 + o2) = make_float2(fsp(v0), fsp(v1));
        }
    }
}

// ---------------- Scan phase 1: per-chunk local states ----------------
__global__ __launch_bounds__(128) void k_scan1(
    const float* __restrict__ dt_g, const u16* __restrict__ u_g,
    const float* __restrict__ B_g, const float* __restrict__ A_log,
    float* __restrict__ hl_ws, float* __restrict__ sdt_ws)
{
    const int d = threadIdx.x, c = blockIdx.x, b = blockIdx.y;
    float A[16];
#pragma unroll
    for (int s = 0; s < 16; s++) A[s] = -__expf(A_log[d * 16 + s]);
    const float A0 = A[0];
    bool chain = true;
#pragma unroll
    for (int s = 1; s < 16; s++)
        chain = chain && (fabsf(A[s] - (float)(s + 1) * A0) <= 1e-4f * fabsf(A[s]));

    float h[16];
#pragma unroll
    for (int s = 0; s < 16; s++) h[s] = 0.f;
    float sdt = 0.f;
    const long long tok0 = (long long)b * L_SZ + (long long)c * CLEN;

    if (chain) {
        for (int i = 0; i < CLEN; i++) {
            const long long t = tok0 + i;
            float dtv = dt_g[t * 128 + d];
            float uv  = bfu2f(u_g[t * 128 + d]);
            const float4* Bp = (const float4*)(B_g + t * 16);
            float4 B0 = Bp[0], B1 = Bp[1], B2 = Bp[2], B3 = Bp[3];
            float Bv[16] = { B0.x, B0.y, B0.z, B0.w, B1.x, B1.y, B1.z, B1.w,
                             B2.x, B2.y, B2.z, B2.w, B3.x, B3.y, B3.z, B3.w };
            float du = dtv * uv;  sdt += dtv;
            float p = __expf(dtv * A0), dA = p;
            h[0] = dA * h[0] + du * Bv[0];
#pragma unroll
            for (int s = 1; s < 16; s++) { dA *= p; h[s] = dA * h[s] + du * Bv[s]; }
        }
    } else {
        for (int i = 0; i < CLEN; i++) {
            const long long t = tok0 + i;
            float dtv = dt_g[t * 128 + d];
            float uv  = bfu2f(u_g[t * 128 + d]);
            const float4* Bp = (const float4*)(B_g + t * 16);
            float4 B0 = Bp[0], B1 = Bp[1], B2 = Bp[2], B3 = Bp[3];
            float Bv[16] = { B0.x, B0.y, B0.z, B0.w, B1.x, B1.y, B1.z, B1.w,
                             B2.x, B2.y, B2.z, B2.w, B3.x, B3.y, B3.z, B3.w };
            float du = dtv * uv;  sdt += dtv;
#pragma unroll
            for (int s = 0; s < 16; s++) h[s] = __expf(dtv * A[s]) * h[s] + du * Bv[s];
        }
    }

    float4* hp4 = (float4*)(hl_ws + (((long long)b * NCH + c) * 128 + d) * 16);
    hp4[0] = make_float4(h[0], h[1], h[2], h[3]);
    hp4[1] = make_float4(h[4], h[5], h[6], h[7]);
    hp4[2] = make_float4(h[8], h[9], h[10], h[11]);
    hp4[3] = make_float4(h[12], h[13], h[14], h[15]);
    sdt_ws[((long long)b * NCH + c) * 128 + d] = sdt;
}

// ---------------- Chunk-boundary combine ----------------
__global__ __launch_bounds__(256) void k_combine(
    const float* __restrict__ A_log, const float* __restrict__ hl_ws,
    const float* __restrict__ sdt_ws, float* __restrict__ hin_ws)
{
    int gid = blockIdx.x * 256 + threadIdx.x;   // 0..32767
    int b = gid >> 11;
    int rem = gid & 2047;     // d*16+s
    int d = rem >> 4;
    float A = -__expf(A_log[rem]);
    float h = 0.f;
    for (int c = 0; c < NCH; c++) {
        long long o = ((long long)b * NCH + c) * 2048 + rem;
        hin_ws[o] = h;
        float sdt = sdt_ws[((long long)b * NCH + c) * 128 + d];
        h = __expf(A * sdt) * h + hl_ws[o];
    }
}

// ---------------- Scan phase 3: final states + y ----------------
__global__ __launch_bounds__(128) void k_scan3(
    const float* __restrict__ dt_g, const u16* __restrict__ u_g,
    const float* __restrict__ B_g, const float* __restrict__ C_g,
    const u16* __restrict__ sz_g, const float* __restrict__ A_log,
    const float* __restrict__ D_skip, const float* __restrict__ hin_ws,
    u16* __restrict__ y_g)
{
    const int d = threadIdx.x, c = blockIdx.x, b = blockIdx.y;
    float A[16];
#pragma unroll
    for (int s = 0; s < 16; s++) A[s] = -__expf(A_log[d * 16 + s]);
    const float A0 = A[0];
    bool chain = true;
#pragma unroll
    for (int s = 1; s < 16; s++)
        chain = chain && (fabsf(A[s] - (float)(s + 1) * A0) <= 1e-4f * fabsf(A[s]));

    float h[16];
    {
        const float4* hp = (const float4*)(hin_ws + (((long long)b * NCH + c) * 128 + d) * 16);
        float4 h0 = hp[0], h1 = hp[1], h2 = hp[2], h3 = hp[3];
        h[0]=h0.x; h[1]=h0.y; h[2]=h0.z; h[3]=h0.w;
        h[4]=h1.x; h[5]=h1.y; h[6]=h1.z; h[7]=h1.w;
        h[8]=h2.x; h[9]=h2.y; h[10]=h2.z; h[11]=h2.w;
        h[12]=h3.x; h[13]=h3.y; h[14]=h3.z; h[15]=h3.w;
    }
    const float Dv = D_skip[d];
    const long long tok0 = (long long)b * L_SZ + (long long)c * CLEN;

    if (chain) {
        for (int i = 0; i < CLEN; i++) {
            const long long t = tok0 + i;
            float dtv = dt_g[t * 128 + d];
            float uv  = bfu2f(u_g[t * 128 + d]);
            const float4* Bp = (const float4*)(B_g + t * 16);
            float4 B0 = Bp[0], B1 = Bp[1], B2 = Bp[2], B3 = Bp[3];
            float Bv[16] = { B0.x, B0.y, B0.z, B0.w, B1.x, B1.y, B1.z, B1.w,
                             B2.x, B2.y, B2.z, B2.w, B3.x, B3.y, B3.z, B3.w };
            const float4* Cp = (const float4*)(C_g + t * 16);
            float4 C0 = Cp[0], C1 = Cp[1], C2 = Cp[2], C3 = Cp[3];
            float Cv[16] = { C0.x, C0.y, C0.z, C0.w, C1.x, C1.y, C1.z, C1.w,
                             C2.x, C2.y, C2.z, C2.w, C3.x, C3.y, C3.z, C3.w };
            float du = dtv * uv;
            float p = __expf(dtv * A0), dA = p;
            h[0] = dA * h[0] + du * Bv[0];
            float ysum = h[0] * Cv[0];
#pragma unroll
            for (int s = 1; s < 16; s++) {
                dA *= p;
                h[s] = dA * h[s] + du * Bv[s];
                ysum += h[s] * Cv[s];
            }
            float szv = bfu2f(sz_g[t * 128 + d]);
            y_g[t * 128 + d] = f2bfu((ysum + uv * Dv) * szv);
        }
    } else {
        for (int i = 0; i < CLEN; i++) {
            const long long t = tok0 + i;
            float dtv = dt_g[t * 128 + d];
            float uv  = bfu2f(u_g[t * 128 + d]);
            const float4* Bp = (const float4*)(B_g + t * 16);
            float4 B0 = Bp[0], B1 = Bp[1], B2 = Bp[2], B3 = Bp[3];
            float Bv[16] = { B0.x, B0.y, B0.z, B0.w, B1.x, B1.y, B1.z, B1.w,
                             B2.x, B2.y, B2.z, B2.w, B3.x, B3.y, B3.z, B3.w };
            const float4* Cp = (const float4*)(C_g + t * 16);
            float4 C0 = Cp[0], C1 = Cp[1], C2 = Cp[2], C3 = Cp[3];
            float Cv[16] = { C0.x, C0.y, C0.z, C0.w, C1.x, C1.y, C1.z, C1.w,
                             C2.x, C2.y, C2.z, C2.w, C3.x, C3.y, C3.z, C3.w };
            float du = dtv * uv;
            float ysum = 0.f;
#pragma unroll
            for (int s = 0; s < 16; s++) {
                h[s] = __expf(dtv * A[s]) * h[s] + du * Bv[s];
                ysum += h[s] * Cv[s];
            }
            float szv = bfu2f(sz_g[t * 128 + d]);
            y_g[t * 128 + d] = f2bfu((ysum + uv * Dv) * szv);
        }
    }
}

// ---------------- Epilogue: out = LN(y @ out_proj + xin)  (R2-proven, 256 thr) ----------------
__global__ __launch_bounds__(256) void k_epilogue(
    const u16* __restrict__ y_g, const float* __restrict__ xin_g,
    const u16* __restrict__ Wf4, const float* __restrict__ gamma,
    const float* __restrict__ beta, float* __restrict__ out)
{
    __shared__ __align__(16) char sm[34048];
    u16*   yA  = (u16*)sm;            // [64][136]
    float* smR = (float*)(sm + 17408);// [64][65]

    const int tid = threadIdx.x;
    const int w = tid >> 6, lane = tid & 63;
    const int n16 = lane & 15, quad = lane >> 4;
    const long long t0 = (long long)blockIdx.x * 64;

    for (int idx = tid; idx < 64 * 64; idx += 256) {
        int r = idx >> 6, cp = idx & 63;
        u32 v = ((const u32*)y_g)[(t0 + r) * 64 + cp];
        *(u32*)((char*)yA + r * 272 + cp * 4) = v;
    }
    __syncthreads();

    {
        s8 bf[4];
#pragma unroll
        for (int ks = 0; ks < 4; ks++)
            bf[ks] = *(const s8*)(Wf4 + ((w * 4 + ks) * 64 + lane) * 8);
#pragma unroll
        for (int m = 0; m < 4; m++) {
            int ar = m * 16 + n16;
            f4 acc = {0.f, 0.f, 0.f, 0.f};
#pragma unroll
            for (int ks = 0; ks < 4; ks++) {
                s8 a = *(const s8*)(yA + ar * PU + ks * 32 + quad * 8);
                acc = MFMA16(a, bf[ks], acc, 0, 0, 0);
            }
#pragma unroll
            for (int reg = 0; reg < 4; reg++) {
                int rr = m * 16 + quad * 4 + reg;
                smR[rr * 65 + w * 16 + n16] = acc[reg];
            }
        }
    }
    __syncthreads();

    {
        int o = tid & 63, wv = tid >> 6;
        float g = gamma[o], bb = beta[o];
        for (int j = 0; j < 16; j++) {
            int rr = wv * 16 + j;
            float r = smR[rr * 65 + o] + xin_g[(t0 + rr) * 64 + o];
            float s = r;
#pragma unroll
            for (int mS = 0; mS < 6; mS++) s += __shfl_xor(s, 1 << mS, 64);
            float mu = s * (1.f / 64.f);
            float dv = r - mu;
            float vs = dv * dv;
#pragma unroll
            for (int mS = 0; mS < 6; mS++) vs += __shfl_xor(vs, 1 << mS, 64);
            out[(t0 + rr) * 64 + o] = g * dv * rsqrtf(vs * (1.f / 64.f) + LN_EPS) + bb;
        }
    }
}

extern "C" void kernel_launch(void* const* d_in, const int* in_sizes, int n_in,
                              void* d_out, int out_size, void* d_ws, size_t ws_size,
                              hipStream_t stream)
{
    const float* x       = (const float*)d_in[0];
    const float* W_in    = (const float*)d_in[1];
    const float* b_in    = (const float*)d_in[2];
    const float* in_proj = (const float*)d_in[3];
    const float* conv_w  = (const float*)d_in[4];
    const float* conv_b  = (const float*)d_in[5];
    const float* x_proj  = (const float*)d_in[6];
    const float* dt_w    = (const float*)d_in[7];
    const float* dt_b    = (const float*)d_in[8];
    const float* A_log   = (const float*)d_in[9];
    const float* D_skip  = (const float*)d_in[10];
    const float* Wout    = (const float*)d_in[11];
    const float* gamma   = (const float*)d_in[12];
    const float* beta    = (const float*)d_in[13];
    float* out = (float*)d_out;

    const long long NT = (long long)B_SZ * L_SZ;  // 131072 tokens
    char* ws = (char*)d_ws;
    float*  xin_g = (float*)ws;   ws += NT * 64 * 4;
    float*  dt_g  = (float*)ws;   ws += NT * 128 * 4;
    float*  B_g   = (float*)ws;   ws += NT * 16 * 4;
    float*  C_g   = (float*)ws;   ws += NT * 16 * 4;
    u16*    u_g   = (u16*)ws;     ws += NT * 128 * 2;
    u16*    sz_g  = (u16*)ws;     ws += NT * 128 * 2;
    u16*    y_g   = (u16*)ws;     ws += NT * 128 * 2;
    float*  hl_ws  = (float*)ws;  ws += (long long)B_SZ * NCH * 2048 * 4;
    float*  sdt_ws = (float*)ws;  ws += (long long)B_SZ * NCH * 128 * 4;
    float*  hin_ws = (float*)ws;  ws += (long long)B_SZ * NCH * 2048 * 4;
    u16* Wf1 = (u16*)ws; ws += 4096 * 2;
    u16* Wf2 = (u16*)ws; ws += 16384 * 2;
    u16* Wf3 = (u16*)ws; ws += 6144 * 2;
    u16* Wf4 = (u16*)ws; ws += 8192 * 2;

    k_prep<<<1, 256, 0, stream>>>(W_in, in_proj, x_proj, Wout, Wf1, Wf2, Wf3, Wf4);

    k_frontend<<<dim3(L_SZ / CH, B_SZ), 256, 0, stream>>>(
        x, b_in, conv_w, conv_b, dt_w, dt_b, Wf1, Wf2, Wf3,
        xin_g, u_g, dt_g, B_g, C_g, sz_g);

    k_scan1<<<dim3(NCH, B_SZ), 128, 0, stream>>>(
        dt_g, u_g, B_g, A_log, hl_ws, sdt_ws);

    k_combine<<<128, 256, 0, stream>>>(A_log, hl_ws, sdt_ws, hin_ws);

    k_scan3<<<dim3(NCH, B_SZ), 128, 0, stream>>>(
        dt_g, u_g, B_g, C_g, sz_g, A_log, D_skip, hin_ws, y_g);

    k_epilogue<<<2048, 256, 0, stream>>>(y_g, xin_g, Wf4, gamma, beta, out);
}